// Round 2
// baseline (343.621 us; speedup 1.0000x reference)
//
#include <hip/hip_runtime.h>

#define N_NODES 100000
#define N_EDGES 1600000
#define D 32
#define TILE 1024
#define NTILES ((N_NODES + TILE - 1) / TILE)  // 98

// ws layout (int32 element offsets)
#define WS_COUNTS   0         // 100000
#define WS_TILEOFF  102400    // 100000
#define WS_CURSOR   204800    // 100000
#define WS_BASERAW  307200    // 128
#define WS_BASE     307456    // 128
#define WS_SORTED   308224    // 1600000 -> ends at 1,908,224 ints = 7.63 MB

// Pass 1: degree count per destination node.
__global__ __launch_bounds__(256) void count_kernel(
    const int* __restrict__ dst, int* __restrict__ counts) {
    int e = blockIdx.x * 256 + threadIdx.x;
    if (e < N_EDGES) atomicAdd(&counts[dst[e]], 1);
}

// Pass 2a: per-1024-tile exclusive scan of counts; emit tile totals.
__global__ __launch_bounds__(1024) void scan_tiles_kernel(
    const int* __restrict__ counts, int* __restrict__ tile_off,
    int* __restrict__ base_raw) {
    __shared__ int s[TILE];
    int t = threadIdx.x;
    int g = blockIdx.x * TILE + t;
    int v = (g < N_NODES) ? counts[g] : 0;
    s[t] = v;
    __syncthreads();
    for (int off = 1; off < TILE; off <<= 1) {
        int add = (t >= off) ? s[t - off] : 0;
        __syncthreads();
        s[t] += add;
        __syncthreads();
    }
    if (g < N_NODES) tile_off[g] = s[t] - v;  // exclusive within tile
    if (t == TILE - 1) base_raw[blockIdx.x] = s[t];
}

// Pass 2b: exclusive scan of the 98 tile totals (single block).
__global__ __launch_bounds__(128) void scan_base_kernel(
    const int* __restrict__ base_raw, int* __restrict__ base) {
    __shared__ int s[128];
    int t = threadIdx.x;
    int v = (t < NTILES) ? base_raw[t] : 0;
    s[t] = v;
    __syncthreads();
    for (int off = 1; off < 128; off <<= 1) {
        int add = (t >= off) ? s[t - off] : 0;
        __syncthreads();
        s[t] += add;
        __syncthreads();
    }
    if (t < NTILES) base[t] = s[t] - v;
}

// Pass 3: bin edges by dst (counting-sort scatter of src ids).
__global__ __launch_bounds__(256) void fill_kernel(
    const int* __restrict__ src, const int* __restrict__ dst,
    const int* __restrict__ tile_off, const int* __restrict__ base,
    int* __restrict__ cursor, int* __restrict__ sorted_src) {
    int e = blockIdx.x * 256 + threadIdx.x;
    if (e >= N_EDGES) return;
    int d = dst[e];
    int pos = atomicAdd(&cursor[d], 1);
    sorted_src[tile_off[d] + base[d >> 10] + pos] = src[e];
}

// Pass 4: one wave per node: gather+sum x[src] rows (no atomics), then
// out[n] = agg @ W^T, written once. Block = 256 = 4 waves = 4 nodes.
__global__ __launch_bounds__(256) void aggregate_kernel(
    const float* __restrict__ x, const float* __restrict__ W,
    const int* __restrict__ counts, const int* __restrict__ tile_off,
    const int* __restrict__ base, const int* __restrict__ sorted_src,
    float* __restrict__ out) {
    __shared__ float Wt[D * D];     // Wt[k*32+o] = W[o*32+k] (bank = o, conflict-free)
    __shared__ float aggS[4 * D];   // per-wave aggregated row
    int t = threadIdx.x;
#pragma unroll
    for (int i = t; i < D * D; i += 256) {
        int o = i >> 5, k = i & 31;
        Wt[k * D + o] = W[i];
    }
    __syncthreads();

    int wave = t >> 6;
    int lane = t & 63;
    int n = blockIdx.x * 4 + wave;
    if (n >= N_NODES) return;

    int h = lane >> 5;   // half-wave: which of 2 edges per iteration
    int f = lane & 31;   // feature index
    int start = tile_off[n] + base[n >> 10];
    int cnt = counts[n];

    float acc = 0.f;
    for (int i = h; i < cnt; i += 2) {
        int s = sorted_src[start + i];
        acc += x[s * D + f];   // two coalesced 128B row gathers per wave-instr
    }
    acc += __shfl_xor(acc, 32);      // combine the two half-wave partials
    if (h == 0) aggS[wave * D + f] = acc;  // same-wave LDS write->read, ordered

    // out[n][o=f] = sum_k agg[k] * W[o][k]; split k-range across half-waves
    float r = 0.f;
#pragma unroll
    for (int kk = 0; kk < 16; ++kk) {
        int k = h * 16 + kk;
        r += aggS[wave * D + k] * Wt[k * D + f];  // agg: broadcast; Wt: 2-way (free)
    }
    r += __shfl_xor(r, 32);
    if (h == 0) out[n * D + f] = r;
}

extern "C" void kernel_launch(void* const* d_in, const int* in_sizes, int n_in,
                              void* d_out, int out_size, void* d_ws, size_t ws_size,
                              hipStream_t stream) {
    const float* x = (const float*)d_in[0];
    const int* edge_index = (const int*)d_in[1];  // [2, N_EDGES] int32
    const float* W = (const float*)d_in[2];
    float* out = (float*)d_out;
    int* ws = (int*)d_ws;

    const int* src = edge_index;
    const int* dst = edge_index + N_EDGES;

    int* counts   = ws + WS_COUNTS;
    int* tile_off = ws + WS_TILEOFF;
    int* cursor   = ws + WS_CURSOR;
    int* base_raw = ws + WS_BASERAW;
    int* base     = ws + WS_BASE;
    int* sorted   = ws + WS_SORTED;

    // zero counts..cursor (ws is re-poisoned to 0xAA each call)
    hipMemsetAsync(ws, 0, (size_t)(WS_CURSOR + N_NODES) * sizeof(int), stream);

    int eblocks = (N_EDGES + 255) / 256;  // 6250
    count_kernel<<<eblocks, 256, 0, stream>>>(dst, counts);
    scan_tiles_kernel<<<NTILES, TILE, 0, stream>>>(counts, tile_off, base_raw);
    scan_base_kernel<<<1, 128, 0, stream>>>(base_raw, base);
    fill_kernel<<<eblocks, 256, 0, stream>>>(src, dst, tile_off, base, cursor, sorted);

    int ablocks = (N_NODES + 3) / 4;  // 25000
    aggregate_kernel<<<ablocks, 256, 0, stream>>>(x, W, counts, tile_off, base, sorted, out);
    // out is fully written by aggregate_kernel (every node row) -> no output memset needed
}